// Round 13
// baseline (174.789 us; speedup 1.0000x reference)
//
#include <hip/hip_runtime.h>
#include <hip/hip_fp16.h>

typedef _Float16 f16;
typedef _Float16 f16x4 __attribute__((ext_vector_type(4)));
typedef _Float16 f16x8 __attribute__((ext_vector_type(8)));
typedef float f32x4 __attribute__((ext_vector_type(4)));

#define NCH 64          // chunks of 32 rows per batch
#define CHB 32768       // raw bytes per chunk (32 rows x 256 f32)
#define PLB 16384       // plane bytes per chunk (32 rows x 256 f16)
#define PSTRIDE 524288  // psc plane stride (floats) = 256*2048

#define BAR()     asm volatile("s_waitcnt lgkmcnt(0)\n\ts_barrier" ::: "memory")
#define WAITV_(N) asm volatile("s_waitcnt vmcnt(" #N ")" ::: "memory")
#define WAITV(N)  WAITV_(N)

// ---------------------------------------------------------------------------
// prep_w: W[0][d][k] (k<256, feature half) -> fp16 HI plane (RTN), MFMA B-frag
// order [ks(8)][ct(16)][lane(64)][j(8)]: ct=d>>4, lane=(d&15)|(((k>>3)&3)<<4),
// ks=k>>5, j=k&7. Frag (ks,ct) = contiguous 1 KiB.
// ---------------------------------------------------------------------------
__global__ void prep_w(const float* __restrict__ W, f16* __restrict__ wbuf) {
    int idx = blockIdx.x * 256 + threadIdx.x;   // 65536 total
    int d = idx >> 8, k = idx & 255;
    float w = W[d * 512 + k];
    int ct   = d >> 4;
    int lane = (d & 15) | (((k >> 3) & 3) << 4);
    int ks   = k >> 5;
    int j    = k & 7;
    wbuf[(((ks * 16 + ct) * 64) + lane) * 8 + j] = (f16)w;
}

// ---------------------------------------------------------------------------
// prep_c: c[b][d] = sum_e W[0][d][256+e] * h[b][e]   (fp32 exact, tiny)
// ---------------------------------------------------------------------------
__global__ void prep_c(const float* __restrict__ W, const float* __restrict__ h,
                       float* __restrict__ c) {
    __shared__ float hs[256];
    int b = blockIdx.x, d = threadIdx.x;
    hs[d] = h[b * 256 + d];
    __syncthreads();
    const float4* w4 = (const float4*)(W + d * 512 + 256);
    const float4* h4 = (const float4*)hs;
    float acc = 0.f;
#pragma unroll 8
    for (int e = 0; e < 64; ++e) {
        float4 a = w4[e], bb = h4[e];
        acc += a.x * bb.x + a.y * bb.y + a.z * bb.z + a.w * bb.w;
    }
    c[b * 256 + d] = acc;
}

// ---------------------------------------------------------------------------
// main_gemm: software-pipelined single-pass f16.
// Per step T (one 32-row chunk), ONE barrier:
//   BAR -> ISSUE(T+2) -> WAITV(4) -> ks-loop: { ds_read A + 4 MFMA(T) }
//   interleaved with { CVT round r of chunk T+1 } (even ks) and
//   { EPI slice r of chunk T-1 } (odd ks)  -> psc store(T-1).
// Ping-pong acc arrays (accA/accB) keep all indexing static (rule #20).
// EPI/CVT VALU+LDS co-issue with the MFMA pipe -> serial tail hidden.
// raw ring 2x32K (linear fp32 DMA), planes 2x16K f16 XOR-swizzled.
// 8 waves = 2 row-halves x 4 col-groups; wave = 16 rows x 64 cols.
// ---------------------------------------------------------------------------
__global__ __launch_bounds__(512, 2)
void main_gemm(const float* __restrict__ feat, const f16* __restrict__ wbuf,
               const float* __restrict__ cb, const float* __restrict__ vvec,
               float* __restrict__ psc) {
    __shared__ __align__(16) char rawb[2 * CHB];    // 64 KiB fp32 ring
    __shared__ __align__(16) char plnb[2 * PLB];    // 32 KiB f16 planes

    const int tid = threadIdx.x;
    const int w = tid >> 6;       // wave 0..7
    const int l = tid & 63;
    const int g = l >> 4;         // 0..3
    const int lr = l & 15;
    const int rh = w >> 2;        // row-half 0/1
    const int cg = w & 3;         // col-group 0..3 (64 cols each)
    const int b = blockIdx.x;     // batch

    // ---- W-hi fragments for this wave's 64 cols: wf[ct][ks], 128 VGPRs ----
    f16x8 wf[4][8];
    {
        const f16x8* wp = (const f16x8*)wbuf;
#pragma unroll
        for (int ct = 0; ct < 4; ++ct) {
            int ctg = cg * 4 + ct;
#pragma unroll
            for (int ks = 0; ks < 8; ++ks)
                wf[ct][ks] = wp[(ks * 16 + ctg) * 64 + l];
        }
    }
    float c_[4], v_[4];
#pragma unroll
    for (int ct = 0; ct < 4; ++ct) {
        c_[ct] = cb[b * 256 + (cg * 4 + ct) * 16 + lr];
        v_[ct] = vvec[(cg * 4 + ct) * 16 + lr];
    }

    const char* tbb = (const char*)(feat + (size_t)b * 2048 * 256);

#define ISSUE(u)                                                                   \
    {                                                                              \
        const char* nb_ = tbb + (size_t)(u) * CHB;                                 \
        char* Q_ = rawb + ((u) & 1) * CHB;                                         \
        _Pragma("unroll")                                                          \
        for (int i_ = 0; i_ < 4; ++i_)                                             \
            __builtin_amdgcn_global_load_lds(                                      \
                (const __attribute__((address_space(1))) void*)(nb_ + i_ * 8192 + tid * 16), \
                (__attribute__((address_space(3))) void*)(Q_ + i_ * 8192 + tid * 16),\
                16, 0, 0);                                                         \
    }

    // cvt round r: flat elems r*2048 + tid*4 -> row r*8+w, k0=(tid&63)*4
    const int ck0 = (tid & 63) * 4;
    int cvt_off[4];
#pragma unroll
    for (int r = 0; r < 4; ++r) {
        int row = r * 8 + w;
        cvt_off[r] = (((row * 512 + (ck0 & ~7) * 2) ^ ((row & 7) << 4)) +
                      ((ck0 & 4) << 1));
    }

#define CVTR(U, R)                                                                 \
    {                                                                              \
        const char* rp_ = rawb + ((U) & 1) * CHB;                                  \
        char* hq_ = plnb + ((U) & 1) * PLB;                                        \
        f32x4 x_ = *(const f32x4*)(rp_ + (R) * 8192 + tid * 16);                   \
        f16x4 hv_ = {(f16)x_[0], (f16)x_[1], (f16)x_[2], (f16)x_[3]};              \
        *(f16x4*)(hq_ + cvt_off[R]) = hv_;                                         \
    }

    // MFMA-phase A addressing (constant per lane): row = rh*16+lr
    const int arow = rh * 16 + lr;
    const int aswz = (arow & 7) << 4;

#define KS(KSI, ACC)                                                               \
    {                                                                              \
        int ao_ = (arow * 512 + (KSI) * 64 + g * 16) ^ aswz;                       \
        f16x8 ah_ = *(const f16x8*)(hp_ + ao_);                                    \
        ACC[0] = __builtin_amdgcn_mfma_f32_16x16x32_f16(ah_, wf[0][KSI], ACC[0], 0, 0, 0); \
        ACC[1] = __builtin_amdgcn_mfma_f32_16x16x32_f16(ah_, wf[1][KSI], ACC[1], 0, 0, 0); \
        ACC[2] = __builtin_amdgcn_mfma_f32_16x16x32_f16(ah_, wf[2][KSI], ACC[2], 0, 0, 0); \
        ACC[3] = __builtin_amdgcn_mfma_f32_16x16x32_f16(ah_, wf[3][KSI], ACC[3], 0, 0, 0); \
    }

#define EPIS(ACCP, R, SV)                                                          \
    {                                                                              \
        float a_ = 0.f;                                                            \
        _Pragma("unroll")                                                          \
        for (int ct_ = 0; ct_ < 4; ++ct_) {                                        \
            float x_ = ACCP[ct_][R] + c_[ct_];                                     \
            float t_ = 1.f - __fdividef(2.f, __expf(2.f * x_) + 1.f);              \
            a_ += v_[ct_] * t_;                                                    \
        }                                                                          \
        a_ += __shfl_xor(a_, 1, 64);                                               \
        a_ += __shfl_xor(a_, 2, 64);                                               \
        a_ += __shfl_xor(a_, 4, 64);                                               \
        a_ += __shfl_xor(a_, 8, 64);                                               \
        SV = a_;                                                                   \
    }

#define STEP(T, ACC, ACCP, DOISS, WS, DOCVT)                                       \
    {                                                                              \
        BAR();                                                                     \
        if (DOISS) ISSUE((T) + 2);                                                 \
        WS;                                                                        \
        const char* hp_ = plnb + ((T) & 1) * PLB;                                  \
        ACC[0] = zf; ACC[1] = zf; ACC[2] = zf; ACC[3] = zf;                        \
        float sA_, sB_, sC_, sD_;                                                  \
        KS(0, ACC) if (DOCVT) CVTR((T) + 1, 0)                                     \
        KS(1, ACC) EPIS(ACCP, 0, sA_)                                              \
        KS(2, ACC) if (DOCVT) CVTR((T) + 1, 1)                                     \
        KS(3, ACC) EPIS(ACCP, 1, sB_)                                              \
        KS(4, ACC) if (DOCVT) CVTR((T) + 1, 2)                                     \
        KS(5, ACC) EPIS(ACCP, 2, sC_)                                              \
        KS(6, ACC) if (DOCVT) CVTR((T) + 1, 3)                                     \
        KS(7, ACC) EPIS(ACCP, 3, sD_)                                              \
        if ((T) > 0 && lr == 0) {                                                  \
            size_t rowg = (size_t)b * 2048 + (size_t)((T) - 1) * 32 + rh * 16 + g * 4; \
            float4 o_ = {sA_, sB_, sC_, sD_};                                      \
            *(float4*)(psc + (size_t)cg * PSTRIDE + rowg) = o_;                    \
        }                                                                          \
    }

    const f32x4 zf = {0.f, 0.f, 0.f, 0.f};
    f32x4 accA[4] = {zf, zf, zf, zf};
    f32x4 accB[4] = {zf, zf, zf, zf};

    // ---- prologue: DMA chunks 0,1; cvt chunk 0 ----
    ISSUE(0); ISSUE(1);
    WAITV(4);            // raw[0] complete (raw[1] still flying)
    CVTR(0, 0) CVTR(0, 1) CVTR(0, 2) CVTR(0, 3)

    // ---- steady: t = 0..61 (ping-pong acc; EPI of t-1 + CVT of t+1 inside) --
    for (int tt = 0; tt < 31; ++tt) {
        const int t0 = 2 * tt;
        STEP(t0,     accA, accB, 1, WAITV(4), 1)
        STEP(t0 + 1, accB, accA, 1, WAITV(4), 1)
    }
    // ---- t = 62: no new DMA; retire chunk 63's loads (store may remain) ----
    STEP(62, accA, accB, 0, WAITV(1), 1)
    // ---- t = 63: pure compute + EPI(62) ----
    STEP(63, accB, accA, 0, ((void)0), 0)
    // ---- final epilogue for chunk 63 (in accB) ----
    {
        float s0_, s1_, s2_, s3_;
        EPIS(accB, 0, s0_) EPIS(accB, 1, s1_) EPIS(accB, 2, s2_) EPIS(accB, 3, s3_)
        if (lr == 0) {
            size_t rowg = (size_t)b * 2048 + (size_t)63 * 32 + rh * 16 + g * 4;
            float4 o_ = {s0_, s1_, s2_, s3_};
            *(float4*)(psc + (size_t)cg * PSTRIDE + rowg) = o_;
        }
    }
#undef ISSUE
#undef CVTR
#undef KS
#undef EPIS
#undef STEP
}

// ---------------------------------------------------------------------------
// softmax over n (2048) per b, summing 4 plane partials per row.
// ---------------------------------------------------------------------------
__global__ void softmax_k(const float* __restrict__ psc, float* __restrict__ out) {
    __shared__ float red[16];
    int b = blockIdx.x, tid = threadIdx.x;  // 256 threads
    float sc[8];
    float m = -3.4e38f;
#pragma unroll
    for (int q = 0; q < 8; ++q) {
        size_t row = (size_t)b * 2048 + q * 256 + tid;
        sc[q] = (psc[row] + psc[PSTRIDE + row]) +
                (psc[2 * PSTRIDE + row] + psc[3 * PSTRIDE + row]);
        m = fmaxf(m, sc[q]);
    }
#pragma unroll
    for (int d = 1; d < 64; d <<= 1) m = fmaxf(m, __shfl_xor(m, d, 64));
    if ((tid & 63) == 0) red[tid >> 6] = m;
    __syncthreads();
    m = fmaxf(fmaxf(red[0], red[1]), fmaxf(red[2], red[3]));
    float e[8], sum = 0.f;
#pragma unroll
    for (int q = 0; q < 8; ++q) { e[q] = __expf(sc[q] - m); sum += e[q]; }
#pragma unroll
    for (int d = 1; d < 64; d <<= 1) sum += __shfl_xor(sum, d, 64);
    if ((tid & 63) == 0) red[8 + (tid >> 6)] = sum;
    __syncthreads();
    sum = (red[8] + red[9]) + (red[10] + red[11]);
    float inv = __fdividef(1.f, sum);
#pragma unroll
    for (int q = 0; q < 8; ++q)
        out[(size_t)b * 2048 + q * 256 + tid] = e[q] * inv;
}

// ---------------------------------------------------------------------------
extern "C" void kernel_launch(void* const* d_in, const int* in_sizes, int n_in,
                              void* d_out, int out_size, void* d_ws, size_t ws_size,
                              hipStream_t stream) {
    const float* feat = (const float*)d_in[0];   // [256,2048,256]
    const float* h    = (const float*)d_in[1];   // [256,256]
    const float* v    = (const float*)d_in[2];   // [256]
    const float* W    = (const float*)d_in[3];   // [256,512]
    float* out = (float*)d_out;                  // [256,1,2048]

    f16*   wbuf = (f16*)d_ws;                         // 131072 B (hi plane)
    float* cbuf = (float*)((char*)d_ws + 131072);     // 262144 B
    float* psc  = (float*)((char*)d_ws + 524288);     // 4 planes x 2 MiB

    prep_w<<<256, 256, 0, stream>>>(W, wbuf);
    prep_c<<<256, 256, 0, stream>>>(W, h, cbuf);
    main_gemm<<<256, 512, 0, stream>>>(feat, wbuf, cbuf, v, psc);
    softmax_k<<<256, 256, 0, stream>>>(psc, out);
}